// Round 17
// baseline (233.723 us; speedup 1.0000x reference)
//
#include <hip/hip_runtime.h>
#include <stdint.h>

#define E_N 16
#define HID 2048
#define INTER_D 4096
#define NPAIR 2048
#define NTOK 1024
#define CAP 256

typedef __attribute__((ext_vector_type(8))) short bf16x8;
typedef __attribute__((ext_vector_type(4))) float f32x4;
typedef __attribute__((ext_vector_type(2))) unsigned int u32x2;

static __device__ __forceinline__ unsigned short f2bf(float f) {
  union { float f; unsigned int u; } x; x.f = f;
  unsigned int r = x.u + 0x7fffu + ((x.u >> 16) & 1u);
  return (unsigned short)(r >> 16);
}

// pack 2 fp32 -> 2 bf16 in one VALU op (gfx950; no builtin, inline asm per T12/m240)
static __device__ __forceinline__ unsigned int cvt_pk_bf16(float lo, float hi) {
  unsigned int u;
  asm("v_cvt_pk_bf16_f32 %0, %1, %2" : "=v"(u) : "v"(lo), "v"(hi));
  return u;
}

// non-temporal 16B load: single-use weight stream bypasses L2 retention,
// preserving L2 residency for the A-tiles that ARE re-read every K-tile.
static __device__ __forceinline__ f32x4 ntload(const float* p) {
  return __builtin_nontemporal_load(reinterpret_cast<const f32x4*>(p));
}

// ---------------- routing: per-expert pair lists ----------------
__global__ void route_kernel(const int* __restrict__ idx, int* __restrict__ counts,
                             int* __restrict__ gidlist) {
  __shared__ int cnt[E_N];
  const int tid = threadIdx.x;
  if (tid < E_N) cnt[tid] = 0;
  for (int j = tid; j < E_N * CAP; j += 256) gidlist[j] = 0;  // pad with valid gid 0
  __syncthreads();
  for (int p = tid; p < NPAIR; p += 256) {
    int e = idx[p] & 15;
    int pos = atomicAdd(&cnt[e], 1);
    if (pos < CAP) gidlist[e * CAP + pos] = p;
  }
  __syncthreads();
  if (tid < E_N) counts[tid] = (cnt[tid] < CAP) ? cnt[tid] : CAP;
}

// ---------------- tokens fp32 -> bf16 ----------------
__global__ void prep_a_kernel(const float* __restrict__ tok, unsigned short* __restrict__ A1) {
  const int i = (blockIdx.x * 256 + threadIdx.x) * 4;
  const float4 v = *reinterpret_cast<const float4*>(tok + i);
  u32x2 o;
  o.x = cvt_pk_bf16(v.x, v.y);
  o.y = cvt_pk_bf16(v.z, v.w);
  __builtin_nontemporal_store(o, reinterpret_cast<u32x2*>(A1 + i));
}

// ---------------- grouped GEMM (R15 structure + NT hbuf stores) ----------------
// MODE 0: h[gid] = bf16(relu(A1[tok(gid)] @ w1[e] + b1[e]))   (KDIM=2048, NDIM=4096)
// MODE 1: out[tok] += tw[gid] * (h[gid] @ w2[e] + b2[e])      (KDIM=4096, NDIM=2048)
// BM=256, BN=128, BK=64, 16 waves (4M x 4N), per-wave 64x32.
// Pipeline: raw s_barrier + counted vmcnt(4); 2 K-tiles in flight.
// Cache policy: B loads NT (single-use stream, R15's +13us); NEW: G1's hbuf
// epilogue stores NT (16 MB single-write stream, ~2MB/XCD L2 pressure) so the
// re-read A-tiles keep L2 residency in G1 as well.
template <int KDIM, int NDIM, int MODE>
__global__ __launch_bounds__(1024, 4) void moe_gemm_kernel(
    const unsigned short* __restrict__ Asrc,  // bf16 rows, stride KDIM
    const float* __restrict__ W,              // [E][KDIM][NDIM] fp32
    const float* __restrict__ bias,           // [E][NDIM]
    const float* __restrict__ tw,             // [NPAIR] (MODE 1)
    const int* __restrict__ counts,
    const int* __restrict__ gidlist,
    unsigned short* __restrict__ Hout,        // MODE 0
    float* __restrict__ Oout) {               // MODE 1 (atomic)
  constexpr int NC = NDIM / 128;              // n-chunks per expert (32 / 16)
  const int bid = blockIdx.x;
  const int q = bid >> 3;
  const int e = (bid & 7) + 8 * (q / NC);     // XCD (bid&7) owns experts {x, x+8}
  const int n0 = (q % NC) * 128;
  const int ne = counts[e];
  if (ne <= 0) return;
  const int tid = threadIdx.x;
  const int lane = tid & 63;
  const int wv = tid >> 6;   // 0..15
  const int wm = wv >> 2;    // M group of 64 rows
  const int wn = wv & 3;     // N group of 32 cols

  extern __shared__ char smem[];
  char* AsB0 = smem;            // 32 KiB A buf 0 (bf16 [256][64], source-swizzled)
  char* AsB1 = smem + 32768;    // 32 KiB A buf 1
  char* Bs   = smem + 65536;    // 16 KiB B tile bf16 [128 n][64 k], XOR-swizzled
  __shared__ int sgid[CAP];
  if (tid < CAP) sgid[tid] = gidlist[e * CAP + tid];
  __syncthreads();

  // ---- A staging (global_load_lds, dest linear, source pre-swizzled) ----
  const bool astage = (wv * 16) < ne;              // skip all-padding row groups
  const int c16 = (lane & 7) ^ ((lane >> 3) & 7);  // inverse swizzle on source column
  const unsigned short* arp[2];
#pragma unroll
  for (int i = 0; i < 2; ++i) {
    const int row = (wv * 2 + i) * 8 + (lane >> 3);
    const int gid = sgid[row];
    const long arow = (MODE == 0) ? (gid >> 1) : gid;
    arp[i] = Asrc + arow * (long)KDIM + c16 * 8;
  }

  // ---- B staging: thread loads 2 rows(k) x 4 cols(n) fp32, transposes, packs bf16 ----
  const int bn4 = (tid & 31) * 4;
  const int bk2 = (tid >> 5) * 2;
  const float* wbase = W + (long)e * KDIM * NDIM + n0 + bn4;
  int bbyte[4];
#pragma unroll
  for (int c = 0; c < 4; ++c)
    bbyte[c] = (((bn4 + c) * 128) + bk2 * 2) ^ ((tid & 7) << 4);

  auto loadB = [&](int t, f32x4& r0, f32x4& r1) {
    const float* p = wbase + (long)(t * 64 + bk2) * NDIM;
    r0 = ntload(p);
    r1 = ntload(p + NDIM);
  };
  auto writeB = [&](const f32x4& r0, const f32x4& r1) {
#pragma unroll
    for (int c = 0; c < 4; ++c) {
      unsigned int u = cvt_pk_bf16(r0[c], r1[c]);
      *reinterpret_cast<unsigned int*>(Bs + bbyte[c]) = u;
    }
  };
  auto stageA = [&](int t, char* buf) {
    if (!astage) return;
#pragma unroll
    for (int i = 0; i < 2; ++i) {
      char* dst = buf + (wv * 2 + i) * 1024;  // wave-uniform base; HW adds lane*16
      __builtin_amdgcn_global_load_lds(
          (const __attribute__((address_space(1))) void*)(arp[i] + t * 64),
          (__attribute__((address_space(3))) void*)dst, 16, 0, 0);
    }
  };

  // ---- fragment LDS byte offsets ----
  const int rl = lane & 15;
  const int kg = lane >> 4;  // 0..3
  int abyte[4][2], bbyteF[2][2];
#pragma unroll
  for (int mf = 0; mf < 4; ++mf) {
    const int row = wm * 64 + mf * 16 + rl;
#pragma unroll
    for (int ks = 0; ks < 2; ++ks) {
      const int unit = (ks * 4 + kg) ^ (lane & 7);
      abyte[mf][ks] = row * 128 + unit * 16;
    }
  }
#pragma unroll
  for (int nf = 0; nf < 2; ++nf) {
    const int n = wn * 32 + nf * 16 + rl;
#pragma unroll
    for (int ks = 0; ks < 2; ++ks)
      bbyteF[nf][ks] = ((n * 128) + (ks * 32 + kg * 8) * 2) ^ (((n >> 2) & 7) << 4);
  }

  f32x4 acc[4][2];
#pragma unroll
  for (int mf = 0; mf < 4; ++mf)
#pragma unroll
    for (int nf = 0; nf < 2; ++nf) acc[mf][nf] = (f32x4)(0.0f);

  const bool mact = (wm * 64) < ne;  // wave-level skip of all-padding rows
  const int NK = KDIM / 64;          // 32 or 64 (even)

  auto compute = [&](const char* Ab) {
#pragma unroll
    for (int ks = 0; ks < 2; ++ks) {
      bf16x8 af[4], bfr[2];
#pragma unroll
      for (int mf = 0; mf < 4; ++mf)
        af[mf] = *reinterpret_cast<const bf16x8*>(Ab + abyte[mf][ks]);
#pragma unroll
      for (int nf = 0; nf < 2; ++nf)
        bfr[nf] = *reinterpret_cast<const bf16x8*>(Bs + bbyteF[nf][ks]);
#pragma unroll
      for (int mf = 0; mf < 4; ++mf)
#pragma unroll
        for (int nf = 0; nf < 2; ++nf)
          acc[mf][nf] = __builtin_amdgcn_mfma_f32_16x16x32_bf16(
              af[mf], bfr[nf], acc[mf][nf], 0, 0, 0);
    }
  };

  // Statically-named B register sets: even tiles -> brE*, odd tiles -> brO* (rule #20).
  f32x4 brE0, brE1, brO0, brO1;

  // one pipeline step for tile t: compute(t), publish B(t+1), prefetch tile t+2
  auto step = [&](int t, const f32x4& w0, const f32x4& w1,
                  f32x4& l0, f32x4& l1, bool more) {
    char* Ab = (t & 1) ? AsB1 : AsB0;
    if (more) loadB(t + 2, l0, l1);           // issue early, in flight across barriers
    if (mact) compute(Ab);
    asm volatile("s_waitcnt lgkmcnt(0)" ::: "memory");  // my ds reads done pre-overwrite
    asm volatile("s_barrier" ::: "memory");             // all readers of Ab/Bs done
    if (more) {
      stageA(t + 2, Ab);                      // overwrite just-freed A buffer
      asm volatile("s_waitcnt vmcnt(4)" ::: "memory");  // tile t+1 ops arrived;
      writeB(w0, w1);                                   // tile t+2 ops stay in flight
    } else {
      asm volatile("s_waitcnt vmcnt(0)" ::: "memory");
      writeB(w0, w1);
    }
    asm volatile("s_waitcnt lgkmcnt(0)" ::: "memory");  // Bs writes visible
    asm volatile("s_barrier" ::: "memory");             // publish Bs(t+1) / A(t+1)
  };

  // ---- prologue: tiles 0 and 1 in flight ----
  loadB(0, brE0, brE1); stageA(0, AsB0);
  loadB(1, brO0, brO1); stageA(1, AsB1);
  asm volatile("s_waitcnt vmcnt(4)" ::: "memory");  // tile 0 arrived
  writeB(brE0, brE1);
  asm volatile("s_waitcnt lgkmcnt(0)" ::: "memory");
  asm volatile("s_barrier" ::: "memory");

  // ---- main loop: t = 0 .. NK-3 (paired for static reg parity) ----
  for (int t2 = 0; t2 < NK - 2; t2 += 2) {
    step(t2,     brO0, brO1, brE0, brE1, true);   // even t: publish odd, load even
    step(t2 + 1, brE0, brE1, brO0, brO1, true);   // odd t: publish even, load odd
  }
  step(NK - 2, brO0, brO1, brE0, brE1, false);    // last publish, drain to 0
  if (mact) compute(AsB1);                        // tile NK-1 (odd buffer)

  // ---- epilogue ----
  if (mact) {
    const int rg = (lane >> 4) * 4;
    float bc[2];
#pragma unroll
    for (int nf = 0; nf < 2; ++nf)
      bc[nf] = bias[(long)e * NDIM + n0 + wn * 32 + nf * 16 + rl];
#pragma unroll
    for (int mf = 0; mf < 4; ++mf) {
#pragma unroll
      for (int r = 0; r < 4; ++r) {
        const int row = wm * 64 + mf * 16 + rg + r;
        if (row < ne) {
          const int gid = sgid[row];
#pragma unroll
          for (int nf = 0; nf < 2; ++nf) {
            const int col = n0 + wn * 32 + nf * 16 + rl;
            float v = acc[mf][nf][r] + bc[nf];
            if constexpr (MODE == 0) {
              v = fmaxf(v, 0.0f);
              // NT store: h is not re-read in G1; keep L2 for the A-tiles.
              unsigned short hv = f2bf(v);
              __builtin_nontemporal_store(hv, Hout + (long)gid * NDIM + col);
            } else {
              v *= tw[gid];
              atomicAdd(Oout + (long)(gid >> 1) * NDIM + col, v);
            }
          }
        }
      }
    }
  }
}

extern "C" void kernel_launch(void* const* d_in, const int* in_sizes, int n_in,
                              void* d_out, int out_size, void* d_ws, size_t ws_size,
                              hipStream_t stream) {
  const float* tokens = (const float*)d_in[0];
  const int* idx      = (const int*)d_in[1];
  const float* tw     = (const float*)d_in[2];
  const float* w1     = (const float*)d_in[3];
  const float* b1     = (const float*)d_in[4];
  const float* w2     = (const float*)d_in[5];
  const float* b2     = (const float*)d_in[6];
  float* out = (float*)d_out;

  char* ws = (char*)d_ws;
  int* counts  = (int*)ws;
  int* gidlist = (int*)(ws + 1024);
  unsigned short* A1   = (unsigned short*)(ws + 32768);
  unsigned short* hbuf = (unsigned short*)(ws + 32768 + (size_t)NTOK * HID * 2);

  (void)hipMemsetAsync(out, 0, (size_t)NTOK * HID * sizeof(float), stream);
  route_kernel<<<1, 256, 0, stream>>>(idx, counts, gidlist);
  prep_a_kernel<<<(NTOK * HID / 4) / 256, 256, 0, stream>>>(tokens, A1);

  (void)hipFuncSetAttribute((const void*)moe_gemm_kernel<HID, INTER_D, 0>,
                            hipFuncAttributeMaxDynamicSharedMemorySize, 81920);
  (void)hipFuncSetAttribute((const void*)moe_gemm_kernel<INTER_D, HID, 1>,
                            hipFuncAttributeMaxDynamicSharedMemorySize, 81920);

  // 1-D grids, XCD-aware placement: bid = (e&7) + 8*(nc + NC*(e>>3))
  moe_gemm_kernel<HID, INTER_D, 0><<<E_N * (INTER_D / 128), 1024, 81920, stream>>>(
      A1, w1, b1, nullptr, counts, gidlist, hbuf, nullptr);
  moe_gemm_kernel<INTER_D, HID, 1><<<E_N * (HID / 128), 1024, 81920, stream>>>(
      hbuf, w2, b2, tw, counts, gidlist, nullptr, out);
}

// Round 18
// 214.805 us; speedup vs baseline: 1.0881x; 1.0881x over previous
//
#include <hip/hip_runtime.h>
#include <stdint.h>

#define E_N 16
#define HID 2048
#define INTER_D 4096
#define NPAIR 2048
#define NTOK 1024
#define CAP 256

typedef __attribute__((ext_vector_type(8))) short bf16x8;
typedef __attribute__((ext_vector_type(4))) float f32x4;

static __device__ __forceinline__ unsigned short f2bf(float f) {
  union { float f; unsigned int u; } x; x.f = f;
  unsigned int r = x.u + 0x7fffu + ((x.u >> 16) & 1u);
  return (unsigned short)(r >> 16);
}

// pack 2 fp32 -> 2 bf16 in one VALU op (gfx950; no builtin, inline asm per T12/m240)
static __device__ __forceinline__ unsigned int cvt_pk_bf16(float lo, float hi) {
  unsigned int u;
  asm("v_cvt_pk_bf16_f32 %0, %1, %2" : "=v"(u) : "v"(lo), "v"(hi));
  return u;
}

// non-temporal 16B load: single-use weight stream bypasses L2 retention,
// preserving L2 residency for the A-tiles that ARE re-read every K-tile.
static __device__ __forceinline__ f32x4 ntload(const float* p) {
  return __builtin_nontemporal_load(reinterpret_cast<const f32x4*>(p));
}

// ---------------- routing: per-expert pair lists ----------------
__global__ void route_kernel(const int* __restrict__ idx, int* __restrict__ counts,
                             int* __restrict__ gidlist) {
  __shared__ int cnt[E_N];
  const int tid = threadIdx.x;
  if (tid < E_N) cnt[tid] = 0;
  for (int j = tid; j < E_N * CAP; j += 256) gidlist[j] = 0;  // pad with valid gid 0
  __syncthreads();
  for (int p = tid; p < NPAIR; p += 256) {
    int e = idx[p] & 15;
    int pos = atomicAdd(&cnt[e], 1);
    if (pos < CAP) gidlist[e * CAP + pos] = p;
  }
  __syncthreads();
  if (tid < E_N) counts[tid] = (cnt[tid] < CAP) ? cnt[tid] : CAP;
}

// ---------------- tokens fp32 -> bf16 ----------------
__global__ void prep_a_kernel(const float* __restrict__ tok, unsigned short* __restrict__ A1) {
  const int i = (blockIdx.x * 256 + threadIdx.x) * 4;
  const float4 v = *reinterpret_cast<const float4*>(tok + i);
  unsigned int o0 = cvt_pk_bf16(v.x, v.y);
  unsigned int o1 = cvt_pk_bf16(v.z, v.w);
  uint2 o; o.x = o0; o.y = o1;
  *reinterpret_cast<uint2*>(A1 + i) = o;   // default policy: re-read by G1 same-XCD
}

// ---------------- combine: out[t] = pbuf[2t] + pbuf[2t+1] ----------------
__global__ void combine_kernel(const float* __restrict__ pbuf, float* __restrict__ out) {
  const int i = (blockIdx.x * 256 + threadIdx.x) * 4;   // fp32 element index
  const int t = i >> 11;                                 // token (row of out, 2048 cols)
  const int c = i & 2047;
  const f32x4 a = *reinterpret_cast<const f32x4*>(pbuf + (long)(2 * t) * HID + c);
  const f32x4 b = *reinterpret_cast<const f32x4*>(pbuf + (long)(2 * t + 1) * HID + c);
  *reinterpret_cast<f32x4*>(out + i) = a + b;
}

// ---------------- grouped GEMM (R15 structure; G2 writes pbuf, no atomics) -----
// MODE 0: h[gid] = bf16(relu(A1[tok(gid)] @ w1[e] + b1[e]))   (KDIM=2048, NDIM=4096)
// MODE 1: pbuf[gid] = tw[gid] * (h[gid] @ w2[e] + b2[e])      (KDIM=4096, NDIM=2048)
// BM=256, BN=128, BK=64, 16 waves (4M x 4N), per-wave 64x32.
// Pipeline: raw s_barrier + counted vmcnt(4); 2 K-tiles in flight.
// Cache policy: B loads NT (R15's +13us); hbuf/A1 stores DEFAULT (R17 lesson:
// producer->consumer same-XCD L2 reuse). pbuf stores NT (read once, cross-XCD).
// XCD placement: bid = (e&7) + 8*(nc + NC*(e>>3)); wave-level padding-staging skip.
template <int KDIM, int NDIM, int MODE>
__global__ __launch_bounds__(1024, 4) void moe_gemm_kernel(
    const unsigned short* __restrict__ Asrc,  // bf16 rows, stride KDIM
    const float* __restrict__ W,              // [E][KDIM][NDIM] fp32
    const float* __restrict__ bias,           // [E][NDIM]
    const float* __restrict__ tw,             // [NPAIR] (MODE 1)
    const int* __restrict__ counts,
    const int* __restrict__ gidlist,
    unsigned short* __restrict__ Hout,        // MODE 0
    float* __restrict__ Pout) {               // MODE 1: per-pair rows, no sharing
  constexpr int NC = NDIM / 128;              // n-chunks per expert (32 / 16)
  const int bid = blockIdx.x;
  const int q = bid >> 3;
  const int e = (bid & 7) + 8 * (q / NC);     // XCD (bid&7) owns experts {x, x+8}
  const int n0 = (q % NC) * 128;
  const int ne = counts[e];
  if (ne <= 0) return;
  const int tid = threadIdx.x;
  const int lane = tid & 63;
  const int wv = tid >> 6;   // 0..15
  const int wm = wv >> 2;    // M group of 64 rows
  const int wn = wv & 3;     // N group of 32 cols

  extern __shared__ char smem[];
  char* AsB0 = smem;            // 32 KiB A buf 0 (bf16 [256][64], source-swizzled)
  char* AsB1 = smem + 32768;    // 32 KiB A buf 1
  char* Bs   = smem + 65536;    // 16 KiB B tile bf16 [128 n][64 k], XOR-swizzled
  __shared__ int sgid[CAP];
  if (tid < CAP) sgid[tid] = gidlist[e * CAP + tid];
  __syncthreads();

  // ---- A staging (global_load_lds, dest linear, source pre-swizzled) ----
  const bool astage = (wv * 16) < ne;              // skip all-padding row groups
  const int c16 = (lane & 7) ^ ((lane >> 3) & 7);  // inverse swizzle on source column
  const unsigned short* arp[2];
#pragma unroll
  for (int i = 0; i < 2; ++i) {
    const int row = (wv * 2 + i) * 8 + (lane >> 3);
    const int gid = sgid[row];
    const long arow = (MODE == 0) ? (gid >> 1) : gid;
    arp[i] = Asrc + arow * (long)KDIM + c16 * 8;
  }

  // ---- B staging: thread loads 2 rows(k) x 4 cols(n) fp32, transposes, packs bf16 ----
  const int bn4 = (tid & 31) * 4;
  const int bk2 = (tid >> 5) * 2;
  const float* wbase = W + (long)e * KDIM * NDIM + n0 + bn4;
  int bbyte[4];
#pragma unroll
  for (int c = 0; c < 4; ++c)
    bbyte[c] = (((bn4 + c) * 128) + bk2 * 2) ^ ((tid & 7) << 4);

  auto loadB = [&](int t, f32x4& r0, f32x4& r1) {
    const float* p = wbase + (long)(t * 64 + bk2) * NDIM;
    r0 = ntload(p);
    r1 = ntload(p + NDIM);
  };
  auto writeB = [&](const f32x4& r0, const f32x4& r1) {
#pragma unroll
    for (int c = 0; c < 4; ++c) {
      unsigned int u = cvt_pk_bf16(r0[c], r1[c]);
      *reinterpret_cast<unsigned int*>(Bs + bbyte[c]) = u;
    }
  };
  auto stageA = [&](int t, char* buf) {
    if (!astage) return;
#pragma unroll
    for (int i = 0; i < 2; ++i) {
      char* dst = buf + (wv * 2 + i) * 1024;  // wave-uniform base; HW adds lane*16
      __builtin_amdgcn_global_load_lds(
          (const __attribute__((address_space(1))) void*)(arp[i] + t * 64),
          (__attribute__((address_space(3))) void*)dst, 16, 0, 0);
    }
  };

  // ---- fragment LDS byte offsets ----
  const int rl = lane & 15;
  const int kg = lane >> 4;  // 0..3
  int abyte[4][2], bbyteF[2][2];
#pragma unroll
  for (int mf = 0; mf < 4; ++mf) {
    const int row = wm * 64 + mf * 16 + rl;
#pragma unroll
    for (int ks = 0; ks < 2; ++ks) {
      const int unit = (ks * 4 + kg) ^ (lane & 7);
      abyte[mf][ks] = row * 128 + unit * 16;
    }
  }
#pragma unroll
  for (int nf = 0; nf < 2; ++nf) {
    const int n = wn * 32 + nf * 16 + rl;
#pragma unroll
    for (int ks = 0; ks < 2; ++ks)
      bbyteF[nf][ks] = ((n * 128) + (ks * 32 + kg * 8) * 2) ^ (((n >> 2) & 7) << 4);
  }

  f32x4 acc[4][2];
#pragma unroll
  for (int mf = 0; mf < 4; ++mf)
#pragma unroll
    for (int nf = 0; nf < 2; ++nf) acc[mf][nf] = (f32x4)(0.0f);

  const bool mact = (wm * 64) < ne;  // wave-level skip of all-padding rows
  const int NK = KDIM / 64;          // 32 or 64 (even)

  auto compute = [&](const char* Ab) {
#pragma unroll
    for (int ks = 0; ks < 2; ++ks) {
      bf16x8 af[4], bfr[2];
#pragma unroll
      for (int mf = 0; mf < 4; ++mf)
        af[mf] = *reinterpret_cast<const bf16x8*>(Ab + abyte[mf][ks]);
#pragma unroll
      for (int nf = 0; nf < 2; ++nf)
        bfr[nf] = *reinterpret_cast<const bf16x8*>(Bs + bbyteF[nf][ks]);
#pragma unroll
      for (int mf = 0; mf < 4; ++mf)
#pragma unroll
        for (int nf = 0; nf < 2; ++nf)
          acc[mf][nf] = __builtin_amdgcn_mfma_f32_16x16x32_bf16(
              af[mf], bfr[nf], acc[mf][nf], 0, 0, 0);
    }
  };

  // Statically-named B register sets: even tiles -> brE*, odd tiles -> brO* (rule #20).
  f32x4 brE0, brE1, brO0, brO1;

  // one pipeline step for tile t: compute(t), publish B(t+1), prefetch tile t+2
  auto step = [&](int t, const f32x4& w0, const f32x4& w1,
                  f32x4& l0, f32x4& l1, bool more) {
    char* Ab = (t & 1) ? AsB1 : AsB0;
    if (more) loadB(t + 2, l0, l1);           // issue early, in flight across barriers
    if (mact) compute(Ab);
    asm volatile("s_waitcnt lgkmcnt(0)" ::: "memory");  // my ds reads done pre-overwrite
    asm volatile("s_barrier" ::: "memory");             // all readers of Ab/Bs done
    if (more) {
      stageA(t + 2, Ab);                      // overwrite just-freed A buffer
      asm volatile("s_waitcnt vmcnt(4)" ::: "memory");  // tile t+1 ops arrived;
      writeB(w0, w1);                                   // tile t+2 ops stay in flight
    } else {
      asm volatile("s_waitcnt vmcnt(0)" ::: "memory");
      writeB(w0, w1);
    }
    asm volatile("s_waitcnt lgkmcnt(0)" ::: "memory");  // Bs writes visible
    asm volatile("s_barrier" ::: "memory");             // publish Bs(t+1) / A(t+1)
  };

  // ---- prologue: tiles 0 and 1 in flight ----
  loadB(0, brE0, brE1); stageA(0, AsB0);
  loadB(1, brO0, brO1); stageA(1, AsB1);
  asm volatile("s_waitcnt vmcnt(4)" ::: "memory");  // tile 0 arrived
  writeB(brE0, brE1);
  asm volatile("s_waitcnt lgkmcnt(0)" ::: "memory");
  asm volatile("s_barrier" ::: "memory");

  // ---- main loop: t = 0 .. NK-3 (paired for static reg parity) ----
  for (int t2 = 0; t2 < NK - 2; t2 += 2) {
    step(t2,     brO0, brO1, brE0, brE1, true);   // even t: publish odd, load even
    step(t2 + 1, brE0, brE1, brO0, brO1, true);   // odd t: publish even, load odd
  }
  step(NK - 2, brO0, brO1, brE0, brE1, false);    // last publish, drain to 0
  if (mact) compute(AsB1);                        // tile NK-1 (odd buffer)

  // ---- epilogue ----
  if (mact) {
    const int rg = (lane >> 4) * 4;
    float bc[2];
#pragma unroll
    for (int nf = 0; nf < 2; ++nf)
      bc[nf] = bias[(long)e * NDIM + n0 + wn * 32 + nf * 16 + rl];
#pragma unroll
    for (int mf = 0; mf < 4; ++mf) {
#pragma unroll
      for (int r = 0; r < 4; ++r) {
        const int row = wm * 64 + mf * 16 + rg + r;
        if (row < ne) {
          const int gid = sgid[row];
#pragma unroll
          for (int nf = 0; nf < 2; ++nf) {
            const int col = n0 + wn * 32 + nf * 16 + rl;
            float v = acc[mf][nf][r] + bc[nf];
            if constexpr (MODE == 0) {
              v = fmaxf(v, 0.0f);
              Hout[(long)gid * NDIM + col] = f2bf(v);  // default: G2 re-reads same-XCD
            } else {
              v *= tw[gid];
              // private per-pair row; NT (read once by combine, cross-XCD)
              __builtin_nontemporal_store(v, Pout + (long)gid * NDIM + col);
            }
          }
        }
      }
    }
  }
}

extern "C" void kernel_launch(void* const* d_in, const int* in_sizes, int n_in,
                              void* d_out, int out_size, void* d_ws, size_t ws_size,
                              hipStream_t stream) {
  const float* tokens = (const float*)d_in[0];
  const int* idx      = (const int*)d_in[1];
  const float* tw     = (const float*)d_in[2];
  const float* w1     = (const float*)d_in[3];
  const float* b1     = (const float*)d_in[4];
  const float* w2     = (const float*)d_in[5];
  const float* b2     = (const float*)d_in[6];
  float* out = (float*)d_out;

  char* ws = (char*)d_ws;
  int* counts  = (int*)ws;
  int* gidlist = (int*)(ws + 1024);
  unsigned short* A1   = (unsigned short*)(ws + 32768);
  unsigned short* hbuf = (unsigned short*)(ws + 32768 + (size_t)NTOK * HID * 2);
  float* pbuf = (float*)(ws + 32768 + (size_t)NTOK * HID * 2 + (size_t)NPAIR * INTER_D * 2);

  route_kernel<<<1, 256, 0, stream>>>(idx, counts, gidlist);
  prep_a_kernel<<<(NTOK * HID / 4) / 256, 256, 0, stream>>>(tokens, A1);

  (void)hipFuncSetAttribute((const void*)moe_gemm_kernel<HID, INTER_D, 0>,
                            hipFuncAttributeMaxDynamicSharedMemorySize, 81920);
  (void)hipFuncSetAttribute((const void*)moe_gemm_kernel<INTER_D, HID, 1>,
                            hipFuncAttributeMaxDynamicSharedMemorySize, 81920);

  // 1-D grids, XCD-aware placement: bid = (e&7) + 8*(nc + NC*(e>>3))
  moe_gemm_kernel<HID, INTER_D, 0><<<E_N * (INTER_D / 128), 1024, 81920, stream>>>(
      A1, w1, b1, nullptr, counts, gidlist, hbuf, nullptr);
  moe_gemm_kernel<INTER_D, HID, 1><<<E_N * (HID / 128), 1024, 81920, stream>>>(
      hbuf, w2, b2, tw, counts, gidlist, nullptr, pbuf);

  // out[t] = pbuf[2t] + pbuf[2t+1]  (replaces memset + 4.2M atomics)
  combine_kernel<<<(NTOK * HID / 4) / 256, 256, 0, stream>>>(pbuf, out);
}